// Round 1
// 195.427 us; speedup vs baseline: 1.0388x; 1.0388x over previous
//
#include <hip/hip_runtime.h>

#define NN 100000   // N_SRC == N_DST
#define FD 64       // IN_SRC == IN_DST == OUT
#define NE 1250000  // E

#define RPB 128                         // dst rows per bucket
#define NBK ((NN + RPB - 1) / RPB)      // 782 buckets
#define NBP 1024                        // padded bucket count (pow2 >= NBK)
#define CAP 2048                        // fixed window per bucket (E[cnt]=1600, sd~40)
#define CH  8192                        // edges per partition block (8-edge=64B avg segments)
#define NCH ((NE + CH - 1) / CH)        // 153 partition blocks
#define NTILE (NN / 16)                 // 6250 MFMA tiles per matrix

typedef __attribute__((ext_vector_type(8))) short bf16x8;
typedef __attribute__((ext_vector_type(4))) float f32x4;

__device__ __forceinline__ short cvt_bf16(float f) {   // RNE
    unsigned u = __float_as_uint(f);
    return (short)((u + 0x7FFFu + ((u >> 16) & 1u)) >> 16);
}
__device__ __forceinline__ float bf2f(unsigned short u) {
    return __uint_as_float(((unsigned)u) << 16);
}

// One 16-row MFMA linear tile: dest[i,c] = bias[c] + sum_k x[i,k]*W[c,k]
// A frag: A[m=lane&15][k=quad*8+j]; B = W^T; C frag: col=lane&15, row=quad*4+r.
__device__ __forceinline__ void linear_tile(
    const float* __restrict__ x, const float* __restrict__ W,
    const float* __restrict__ b, float* outf, unsigned short* outh,
    int row0, int lane)
{
    const int m    = lane & 15;
    const int quad = lane >> 4;
    f32x4 acc[4];
    #pragma unroll
    for (int ct = 0; ct < 4; ct++) acc[ct] = (f32x4){0.f, 0.f, 0.f, 0.f};

    #pragma unroll
    for (int kc = 0; kc < 2; kc++) {
        const int k0 = kc * 32 + quad * 8;
        const float4 x0 = *(const float4*)(x + (size_t)(row0 + m) * FD + k0);
        const float4 x1 = *(const float4*)(x + (size_t)(row0 + m) * FD + k0 + 4);
        bf16x8 a;
        a[0]=cvt_bf16(x0.x); a[1]=cvt_bf16(x0.y); a[2]=cvt_bf16(x0.z); a[3]=cvt_bf16(x0.w);
        a[4]=cvt_bf16(x1.x); a[5]=cvt_bf16(x1.y); a[6]=cvt_bf16(x1.z); a[7]=cvt_bf16(x1.w);
        #pragma unroll
        for (int ct = 0; ct < 4; ct++) {
            const int n = ct * 16 + m;
            const float4 w0 = *(const float4*)(W + n * FD + k0);
            const float4 w1 = *(const float4*)(W + n * FD + k0 + 4);
            bf16x8 f;
            f[0]=cvt_bf16(w0.x); f[1]=cvt_bf16(w0.y); f[2]=cvt_bf16(w0.z); f[3]=cvt_bf16(w0.w);
            f[4]=cvt_bf16(w1.x); f[5]=cvt_bf16(w1.y); f[6]=cvt_bf16(w1.z); f[7]=cvt_bf16(w1.w);
            acc[ct] = __builtin_amdgcn_mfma_f32_16x16x32_bf16(a, f, acc[ct], 0, 0, 0);
        }
    }
    #pragma unroll
    for (int ct = 0; ct < 4; ct++) {
        const int col = ct * 16 + m;
        const float bias = b ? b[col] : 0.0f;
        #pragma unroll
        for (int r = 0; r < 4; r++) {
            const size_t idx = (size_t)(row0 + quad * 4 + r) * FD + col;
            const float v = acc[ct][r] + bias;
            if (outf) outf[idx] = v;
            else      outh[idx] = (unsigned short)cvt_bf16(v);
        }
    }
}

// Both linears in ONE dispatch: tiles [0,NTILE) -> h (bf16), [NTILE,2*NTILE) -> out (fp32)
__global__ __launch_bounds__(256) void lin_both(
    const float* __restrict__ x_src, const float* __restrict__ x_dst,
    const float* __restrict__ W_nei, const float* __restrict__ W_self,
    const float* __restrict__ b_self, unsigned short* __restrict__ h,
    float* __restrict__ out)
{
    const int lane = threadIdx.x & 63;
    const int tile = blockIdx.x * 4 + (threadIdx.x >> 6);
    if (tile < NTILE)
        linear_tile(x_src, W_nei, nullptr, nullptr, h, tile * 16, lane);
    else if (tile < 2 * NTILE)
        linear_tile(x_dst, W_self, b_self, out, nullptr, (tile - NTILE) * 16, lane);
}

// ---------- partition edges into fixed-capacity bucket windows ----------
// 1024 threads (16 waves/block, 2 blocks/CU), 8 edges/thread preloaded for ILP.
__global__ __launch_bounds__(1024) void kplace(
    const int* __restrict__ src, const int* __restrict__ dst,
    const float* __restrict__ ew, int* __restrict__ gcursor,
    int2* __restrict__ sp)
{
    __shared__ int cnt[NBP];
    const int t = threadIdx.x;            // 0..1023
    if (t < NBP) cnt[t] = 0;
    __syncthreads();
    const int e0 = blockIdx.x * CH;

    // pass 1: preload 8 dst values (coalesced, independent), then count
    int d[8];
    #pragma unroll
    for (int k = 0; k < 8; k++) {
        const int e = e0 + t + k * 1024;
        d[k] = (e < NE) ? dst[e] : -1;
    }
    #pragma unroll
    for (int k = 0; k < 8; k++)
        if (d[k] >= 0) atomicAdd(&cnt[d[k] >> 7], 1);
    __syncthreads();

    // reserve dense segments in this bucket's fixed window
    if (t < NBP) {
        const int c = cnt[t];
        cnt[t] = c ? (t * CAP + atomicAdd(&gcursor[t], c)) : 0;
    }
    __syncthreads();

    // pass 2: preload src/ew, then emit (8 stores in flight per thread)
    int s[8]; float w[8];
    #pragma unroll
    for (int k = 0; k < 8; k++) {
        const int e = e0 + t + k * 1024;
        if (e < NE) { s[k] = src[e]; w[k] = ew[e]; }
    }
    #pragma unroll
    for (int k = 0; k < 8; k++) {
        if (d[k] >= 0) {
            const int p = atomicAdd(&cnt[d[k] >> 7], 1);
            sp[p] = make_int2(s[k] | ((d[k] & (RPB - 1)) << 17),
                              __float_as_int(w[k]));
        }
    }
}

// ---------- per-bucket counting sort -> sp2 window + rowstart/rowend ----------
__global__ __launch_bounds__(256) void ksub(
    const int2* __restrict__ sp, const int* __restrict__ gcursor,
    int2* __restrict__ sp2, int* __restrict__ rowstart,
    int* __restrict__ rowend)
{
    __shared__ int hist[RPB];
    __shared__ int cur[RPB];
    const int t = threadIdx.x;
    const int b = blockIdx.x;
    const int s0 = b * CAP;
    const int s1 = s0 + gcursor[b];
    if (t < RPB) hist[t] = 0;
    __syncthreads();
    for (int j = s0 + t; j < s1; j += 256)
        atomicAdd(&hist[sp[j].x >> 17], 1);
    __syncthreads();
    if (t < 64) {                       // wave 0 scans 2 bins per lane
        const int v0 = hist[2*t], v1 = hist[2*t + 1];
        const int s = v0 + v1;
        int inc = s;
        #pragma unroll
        for (int off = 1; off < 64; off <<= 1) {
            int u = __shfl_up(inc, off, 64);
            if (t >= off) inc += u;
        }
        const int ex = inc - s;
        cur[2*t]     = s0 + ex;
        cur[2*t + 1] = s0 + ex + v0;
    }
    __syncthreads();
    const int row0 = b * RPB;
    if (t < RPB && row0 + t < NN) {
        rowstart[row0 + t] = cur[t];
        rowend[row0 + t]   = cur[t] + hist[t];
    }
    __syncthreads();                    // row bounds read cur before scatter bumps it
    for (int j = s0 + t; j < s1; j += 256) {
        const int2 q = sp[j];
        const int p = atomicAdd(&cur[q.x >> 17], 1);
        sp2[p] = q;
    }
}

// ---------- gather v3: 4 edges per load instruction (dwordx2 row-gather) ----------
// lane = q*16 + t. Quad q handles edge (k + j*4 + q); its 16 lanes load one full
// 128B h-row as uint2 (cols 4t..4t+3). Zero-init of the staged sp2 register makes
// out-of-range edges read srow=0 with w=0 -> no cndmask masking needed.
__global__ __launch_bounds__(256) void gather_rows(
    const unsigned short* __restrict__ h, const int* __restrict__ rowstart,
    const int* __restrict__ rowend, const int2* __restrict__ sp2,
    float* __restrict__ out)
{
    const int lane = threadIdx.x & 63;
    const int q    = lane >> 4;          // which edge within a group of 4
    const int t    = lane & 15;          // column group: cols 4t..4t+3
    const int row  = (int)((blockIdx.x * blockDim.x + threadIdx.x) >> 6);
    if (row >= NN) return;
    const int j0 = rowstart[row];
    const int n  = rowend[row] - j0;
    const unsigned tb = (unsigned)t << 3;          // byte offset within row
    float a0 = 0.f, a1 = 0.f, a2 = 0.f, a3 = 0.f;

    for (int kb = 0; kb < n; kb += 64) {
        const int rem = n - kb;
        const int m   = rem < 64 ? rem : 64;
        int2 qv = make_int2(0, 0);
        if (lane < m) qv = sp2[j0 + kb + lane];    // one coalesced 512B load
        for (int k = 0; k < m; k += 16) {
            uint2 dv[4]; float wv[4];
            #pragma unroll
            for (int j = 0; j < 4; j++) {          // 4 loads in flight (16 edges)
                const int kk = k + j * 4 + q;      // < 64 always; >=m lanes hold 0
                const int ax = __shfl(qv.x, kk, 64);
                const int ay = __shfl(qv.y, kk, 64);
                const unsigned off = (((unsigned)(ax & 0x1FFFF)) << 7) | tb;
                wv[j] = __int_as_float(ay);        // 0 for padded edges
                dv[j] = *(const uint2*)((const char*)h + off);
            }
            #pragma unroll
            for (int j = 0; j < 4; j++) {
                const float w = wv[j];
                a0 = fmaf(__uint_as_float(dv[j].x << 16),         w, a0);
                a1 = fmaf(__uint_as_float(dv[j].x & 0xFFFF0000u), w, a1);
                a2 = fmaf(__uint_as_float(dv[j].y << 16),         w, a2);
                a3 = fmaf(__uint_as_float(dv[j].y & 0xFFFF0000u), w, a3);
            }
        }
    }
    // cross-quad reduction: all lanes end with full column sums
    a0 += __shfl_xor(a0, 16, 64); a1 += __shfl_xor(a1, 16, 64);
    a2 += __shfl_xor(a2, 16, 64); a3 += __shfl_xor(a3, 16, 64);
    a0 += __shfl_xor(a0, 32, 64); a1 += __shfl_xor(a1, 32, 64);
    a2 += __shfl_xor(a2, 32, 64); a3 += __shfl_xor(a3, 32, 64);
    if (q == 0) {                                   // coalesced 256B float4 RMW
        float4* p = (float4*)(out + (size_t)row * FD + (t << 2));
        float4 v = *p;
        v.x += a0; v.y += a1; v.z += a2; v.w += a3;
        *p = v;
    }
}

// ---------- fallback (small ws): linears + atomic scatter ----------
__global__ __launch_bounds__(256) void scatter_edges(
    const unsigned short* __restrict__ h, const int* __restrict__ eidx,
    const float* __restrict__ ew, float* __restrict__ out)
{
    const int lane  = threadIdx.x & 63;
    const int gwave = (int)((blockIdx.x * blockDim.x + threadIdx.x) >> 6);
    const int nwave = (int)((gridDim.x * blockDim.x) >> 6);
    const int* __restrict__ src = eidx;
    const int* __restrict__ dst = eidx + NE;
    for (int e = gwave; e < NE; e += nwave) {
        const float v = bf2f(h[(size_t)src[e] * FD + lane]) * ew[e];
        atomicAdd(out + (size_t)dst[e] * FD + lane, v);
    }
}

extern "C" void kernel_launch(void* const* d_in, const int* in_sizes, int n_in,
                              void* d_out, int out_size, void* d_ws, size_t ws_size,
                              hipStream_t stream)
{
    const float* x_src  = (const float*)d_in[0];
    const float* x_dst  = (const float*)d_in[1];
    const int*   eidx   = (const int*)  d_in[2];   // [2,E]: src row then dst row
    const float* ew     = (const float*)d_in[3];
    const float* W_nei  = (const float*)d_in[4];
    const float* W_self = (const float*)d_in[5];
    const float* b_self = (const float*)d_in[6];
    float* out = (float*)d_out;

    const int* src = eidx;
    const int* dst = eidx + NE;

    // workspace layout (16B aligned)
    char* ws = (char*)d_ws;
    size_t off = 0;
    auto alloc = [&](size_t bytes) { char* p = ws + off; off += (bytes + 15) & ~(size_t)15; return p; };
    unsigned short* h = (unsigned short*)alloc((size_t)NN * FD * sizeof(unsigned short)); // 12.8 MB
    int*  gcursor  = (int*) alloc((size_t)NBP * sizeof(int));
    int*  rowstart = (int*) alloc((size_t)NN * sizeof(int));
    int*  rowend   = (int*) alloc((size_t)NN * sizeof(int));
    int2* sp       = (int2*)alloc((size_t)NBP * CAP * sizeof(int2));  // 16 MB
    int2* sp2      = (int2*)alloc((size_t)NBP * CAP * sizeof(int2));  // 16 MB
    const size_t need_main = off;
    const size_t need_h    = (size_t)NN * FD * sizeof(unsigned short);

    const int lin_grid = (2 * NTILE + 3) / 4;     // 3125 blocks, 4 tiles/block

    if (ws_size >= need_main) {
        hipMemsetAsync(gcursor, 0, (size_t)NBP * sizeof(int), stream);
        lin_both<<<lin_grid, 256, 0, stream>>>(x_src, x_dst, W_nei, W_self,
                                               b_self, h, out);
        kplace<<<NCH, 1024, 0, stream>>>(src, dst, ew, gcursor, sp);
        ksub  <<<NBK, 256, 0, stream>>>(sp, gcursor, sp2, rowstart, rowend);
        gather_rows<<<(NN * 64 + 255) / 256, 256, 0, stream>>>(h, rowstart,
                                                               rowend, sp2, out);
    } else if (ws_size >= need_h) {
        lin_both<<<lin_grid, 256, 0, stream>>>(x_src, x_dst, W_nei, W_self,
                                               b_self, h, out);
        scatter_edges<<<2048, 256, 0, stream>>>(h, eidx, ew, out);
    }
}

// Round 2
// 186.437 us; speedup vs baseline: 1.0889x; 1.0482x over previous
//
#include <hip/hip_runtime.h>

#define NN 100000   // N_SRC == N_DST
#define FD 64       // IN_SRC == IN_DST == OUT
#define NE 1250000  // E

#define RPB 128                         // dst rows per bucket
#define NBK ((NN + RPB - 1) / RPB)      // 782 buckets
#define NBP 1024                        // padded bucket count (pow2 >= NBK)
#define CAP 2048                        // fixed window per bucket (E[cnt]=1600, sd~40)
#define CH  8192                        // edges per partition block (8-edge=64B avg segments)
#define NCH ((NE + CH - 1) / CH)        // 153 partition blocks
#define NTILE (NN / 16)                 // 6250 MFMA tiles per matrix

#define TPW 2                           // tiles per wave in lin_both
#define NWM (NTILE / TPW)               // 3125 waves per matrix
#define LIN_GRID ((2 * NWM + 3) / 4)    // 1563 blocks (4 waves/block)

typedef __attribute__((ext_vector_type(8))) short bf16x8;
typedef __attribute__((ext_vector_type(4))) float f32x4;

__device__ __forceinline__ short cvt_bf16(float f) {   // RNE
    unsigned u = __float_as_uint(f);
    return (short)((u + 0x7FFFu + ((u >> 16) & 1u)) >> 16);
}
__device__ __forceinline__ float bf2f(unsigned short u) {
    return __uint_as_float(((unsigned)u) << 16);
}

// ---------- fused linears, v2: 2 tiles/wave, W-in-reg, swapped-operand MFMA ----------
// Swapped mfma(wf, a): D[c][i] with col(lane&15)=i (x row), row(quad*4+r)=c-within-block.
// Each lane's acc[ct] = channels {ct*16+quad*4+r} of row (row0+m) -> contiguous
// float4/ushort4 stores. All 8 x-loads issued upfront; W converted once per wave.
__global__ __launch_bounds__(256) void lin_both(
    const float* __restrict__ x_src, const float* __restrict__ x_dst,
    const float* __restrict__ W_nei, const float* __restrict__ W_self,
    const float* __restrict__ b_self, unsigned short* __restrict__ hbuf,
    float* __restrict__ out)
{
    const int lane = threadIdx.x & 63;
    const int m    = lane & 15;
    const int quad = lane >> 4;
    const int gw   = blockIdx.x * 4 + (threadIdx.x >> 6);
    if (gw >= 2 * NWM) return;
    const bool self = gw >= NWM;
    const int  wm   = self ? gw - NWM : gw;
    const float* __restrict__ x = self ? x_dst : x_src;
    const float* __restrict__ W = self ? W_self : W_nei;

    // all x loads for both tiles upfront: 8 independent float4 loads in flight
    const float* xb = x + (size_t)(wm * (TPW * 16) + m) * FD;
    float4 xv[TPW][4];
    #pragma unroll
    for (int t = 0; t < TPW; t++) {
        const float* xr = xb + (size_t)t * 16 * FD;
        xv[t][0] = *(const float4*)(xr + quad * 8);
        xv[t][1] = *(const float4*)(xr + quad * 8 + 4);
        xv[t][2] = *(const float4*)(xr + 32 + quad * 8);
        xv[t][3] = *(const float4*)(xr + 32 + quad * 8 + 4);
    }

    // W frags (A-operand of the swapped mfma): wf[kc][ct] = W[ct*16+m][kc*32+quad*8 ..+7]
    bf16x8 wf[2][4];
    #pragma unroll
    for (int kc = 0; kc < 2; kc++) {
        #pragma unroll
        for (int ct = 0; ct < 4; ct++) {
            const float4 w0 = *(const float4*)(W + (ct * 16 + m) * FD + kc * 32 + quad * 8);
            const float4 w1 = *(const float4*)(W + (ct * 16 + m) * FD + kc * 32 + quad * 8 + 4);
            bf16x8 f;
            f[0]=cvt_bf16(w0.x); f[1]=cvt_bf16(w0.y); f[2]=cvt_bf16(w0.z); f[3]=cvt_bf16(w0.w);
            f[4]=cvt_bf16(w1.x); f[5]=cvt_bf16(w1.y); f[6]=cvt_bf16(w1.z); f[7]=cvt_bf16(w1.w);
            wf[kc][ct] = f;
        }
    }

    float4 bv[4];
    if (self) {
        #pragma unroll
        for (int ct = 0; ct < 4; ct++)
            bv[ct] = *(const float4*)(b_self + ct * 16 + quad * 4);
    }

    #pragma unroll
    for (int t = 0; t < TPW; t++) {
        bf16x8 a0, a1;
        a0[0]=cvt_bf16(xv[t][0].x); a0[1]=cvt_bf16(xv[t][0].y);
        a0[2]=cvt_bf16(xv[t][0].z); a0[3]=cvt_bf16(xv[t][0].w);
        a0[4]=cvt_bf16(xv[t][1].x); a0[5]=cvt_bf16(xv[t][1].y);
        a0[6]=cvt_bf16(xv[t][1].z); a0[7]=cvt_bf16(xv[t][1].w);
        a1[0]=cvt_bf16(xv[t][2].x); a1[1]=cvt_bf16(xv[t][2].y);
        a1[2]=cvt_bf16(xv[t][2].z); a1[3]=cvt_bf16(xv[t][2].w);
        a1[4]=cvt_bf16(xv[t][3].x); a1[5]=cvt_bf16(xv[t][3].y);
        a1[6]=cvt_bf16(xv[t][3].z); a1[7]=cvt_bf16(xv[t][3].w);

        f32x4 acc[4];
        #pragma unroll
        for (int ct = 0; ct < 4; ct++) {
            f32x4 z = (f32x4){0.f, 0.f, 0.f, 0.f};
            z = __builtin_amdgcn_mfma_f32_16x16x32_bf16(wf[0][ct], a0, z, 0, 0, 0);
            z = __builtin_amdgcn_mfma_f32_16x16x32_bf16(wf[1][ct], a1, z, 0, 0, 0);
            acc[ct] = z;
        }

        const size_t rowbase = (size_t)(wm * (TPW * 16) + t * 16 + m) * FD;
        if (!self) {
            #pragma unroll
            for (int ct = 0; ct < 4; ct++) {
                ushort4 sv;
                sv.x = (unsigned short)cvt_bf16(acc[ct][0]);
                sv.y = (unsigned short)cvt_bf16(acc[ct][1]);
                sv.z = (unsigned short)cvt_bf16(acc[ct][2]);
                sv.w = (unsigned short)cvt_bf16(acc[ct][3]);
                *(ushort4*)(hbuf + rowbase + ct * 16 + quad * 4) = sv;
            }
        } else {
            #pragma unroll
            for (int ct = 0; ct < 4; ct++) {
                float4 v;
                v.x = acc[ct][0] + bv[ct].x;
                v.y = acc[ct][1] + bv[ct].y;
                v.z = acc[ct][2] + bv[ct].z;
                v.w = acc[ct][3] + bv[ct].w;
                *(float4*)(out + rowbase + ct * 16 + quad * 4) = v;
            }
        }
    }
}

// ---------- partition edges into fixed-capacity bucket windows ----------
// 1024 threads (16 waves/block, 2 blocks/CU), 8 edges/thread preloaded for ILP.
__global__ __launch_bounds__(1024) void kplace(
    const int* __restrict__ src, const int* __restrict__ dst,
    const float* __restrict__ ew, int* __restrict__ gcursor,
    int2* __restrict__ sp)
{
    __shared__ int cnt[NBP];
    const int t = threadIdx.x;            // 0..1023
    if (t < NBP) cnt[t] = 0;
    __syncthreads();
    const int e0 = blockIdx.x * CH;

    // pass 1: preload 8 dst values (coalesced, independent), then count
    int d[8];
    #pragma unroll
    for (int k = 0; k < 8; k++) {
        const int e = e0 + t + k * 1024;
        d[k] = (e < NE) ? dst[e] : -1;
    }
    #pragma unroll
    for (int k = 0; k < 8; k++)
        if (d[k] >= 0) atomicAdd(&cnt[d[k] >> 7], 1);
    __syncthreads();

    // reserve dense segments in this bucket's fixed window
    if (t < NBP) {
        const int c = cnt[t];
        cnt[t] = c ? (t * CAP + atomicAdd(&gcursor[t], c)) : 0;
    }
    __syncthreads();

    // pass 2: preload src/ew, then emit (8 stores in flight per thread)
    int s[8]; float w[8];
    #pragma unroll
    for (int k = 0; k < 8; k++) {
        const int e = e0 + t + k * 1024;
        if (e < NE) { s[k] = src[e]; w[k] = ew[e]; }
    }
    #pragma unroll
    for (int k = 0; k < 8; k++) {
        if (d[k] >= 0) {
            const int p = atomicAdd(&cnt[d[k] >> 7], 1);
            sp[p] = make_int2(s[k] | ((d[k] & (RPB - 1)) << 17),
                              __float_as_int(w[k]));
        }
    }
}

// ---------- per-bucket counting sort -> sp2 window + rowstart/rowend ----------
__global__ __launch_bounds__(256) void ksub(
    const int2* __restrict__ sp, const int* __restrict__ gcursor,
    int2* __restrict__ sp2, int* __restrict__ rowstart,
    int* __restrict__ rowend)
{
    __shared__ int hist[RPB];
    __shared__ int cur[RPB];
    const int t = threadIdx.x;
    const int b = blockIdx.x;
    const int s0 = b * CAP;
    const int s1 = s0 + gcursor[b];
    if (t < RPB) hist[t] = 0;
    __syncthreads();
    for (int j = s0 + t; j < s1; j += 256)
        atomicAdd(&hist[sp[j].x >> 17], 1);
    __syncthreads();
    if (t < 64) {                       // wave 0 scans 2 bins per lane
        const int v0 = hist[2*t], v1 = hist[2*t + 1];
        const int s = v0 + v1;
        int inc = s;
        #pragma unroll
        for (int off = 1; off < 64; off <<= 1) {
            int u = __shfl_up(inc, off, 64);
            if (t >= off) inc += u;
        }
        const int ex = inc - s;
        cur[2*t]     = s0 + ex;
        cur[2*t + 1] = s0 + ex + v0;
    }
    __syncthreads();
    const int row0 = b * RPB;
    if (t < RPB && row0 + t < NN) {
        rowstart[row0 + t] = cur[t];
        rowend[row0 + t]   = cur[t] + hist[t];
    }
    __syncthreads();                    // row bounds read cur before scatter bumps it
    for (int j = s0 + t; j < s1; j += 256) {
        const int2 q = sp[j];
        const int p = atomicAdd(&cur[q.x >> 17], 1);
        sp2[p] = q;
    }
}

// ---------- gather v3: 4 edges per load instruction (dwordx2 row-gather) ----------
// lane = q*16 + t. Quad q handles edge (k + j*4 + q); its 16 lanes load one full
// 128B h-row as uint2 (cols 4t..4t+3). Zero-init of the staged sp2 register makes
// out-of-range edges read srow=0 with w=0 -> no cndmask masking needed.
__global__ __launch_bounds__(256) void gather_rows(
    const unsigned short* __restrict__ h, const int* __restrict__ rowstart,
    const int* __restrict__ rowend, const int2* __restrict__ sp2,
    float* __restrict__ out)
{
    const int lane = threadIdx.x & 63;
    const int q    = lane >> 4;          // which edge within a group of 4
    const int t    = lane & 15;          // column group: cols 4t..4t+3
    const int row  = (int)((blockIdx.x * blockDim.x + threadIdx.x) >> 6);
    if (row >= NN) return;
    const int j0 = rowstart[row];
    const int n  = rowend[row] - j0;
    const unsigned tb = (unsigned)t << 3;          // byte offset within row
    float a0 = 0.f, a1 = 0.f, a2 = 0.f, a3 = 0.f;

    for (int kb = 0; kb < n; kb += 64) {
        const int rem = n - kb;
        const int m   = rem < 64 ? rem : 64;
        int2 qv = make_int2(0, 0);
        if (lane < m) qv = sp2[j0 + kb + lane];    // one coalesced 512B load
        for (int k = 0; k < m; k += 16) {
            uint2 dv[4]; float wv[4];
            #pragma unroll
            for (int j = 0; j < 4; j++) {          // 4 loads in flight (16 edges)
                const int kk = k + j * 4 + q;      // < 64 always; >=m lanes hold 0
                const int ax = __shfl(qv.x, kk, 64);
                const int ay = __shfl(qv.y, kk, 64);
                const unsigned off = (((unsigned)(ax & 0x1FFFF)) << 7) | tb;
                wv[j] = __int_as_float(ay);        // 0 for padded edges
                dv[j] = *(const uint2*)((const char*)h + off);
            }
            #pragma unroll
            for (int j = 0; j < 4; j++) {
                const float w = wv[j];
                a0 = fmaf(__uint_as_float(dv[j].x << 16),         w, a0);
                a1 = fmaf(__uint_as_float(dv[j].x & 0xFFFF0000u), w, a1);
                a2 = fmaf(__uint_as_float(dv[j].y << 16),         w, a2);
                a3 = fmaf(__uint_as_float(dv[j].y & 0xFFFF0000u), w, a3);
            }
        }
    }
    // cross-quad reduction: all lanes end with full column sums
    a0 += __shfl_xor(a0, 16, 64); a1 += __shfl_xor(a1, 16, 64);
    a2 += __shfl_xor(a2, 16, 64); a3 += __shfl_xor(a3, 16, 64);
    a0 += __shfl_xor(a0, 32, 64); a1 += __shfl_xor(a1, 32, 64);
    a2 += __shfl_xor(a2, 32, 64); a3 += __shfl_xor(a3, 32, 64);
    if (q == 0) {                                   // coalesced 256B float4 RMW
        float4* p = (float4*)(out + (size_t)row * FD + (t << 2));
        float4 v = *p;
        v.x += a0; v.y += a1; v.z += a2; v.w += a3;
        *p = v;
    }
}

// ---------- fallback (small ws): linears + atomic scatter ----------
__global__ __launch_bounds__(256) void scatter_edges(
    const unsigned short* __restrict__ h, const int* __restrict__ eidx,
    const float* __restrict__ ew, float* __restrict__ out)
{
    const int lane  = threadIdx.x & 63;
    const int gwave = (int)((blockIdx.x * blockDim.x + threadIdx.x) >> 6);
    const int nwave = (int)((gridDim.x * blockDim.x) >> 6);
    const int* __restrict__ src = eidx;
    const int* __restrict__ dst = eidx + NE;
    for (int e = gwave; e < NE; e += nwave) {
        const float v = bf2f(h[(size_t)src[e] * FD + lane]) * ew[e];
        atomicAdd(out + (size_t)dst[e] * FD + lane, v);
    }
}

extern "C" void kernel_launch(void* const* d_in, const int* in_sizes, int n_in,
                              void* d_out, int out_size, void* d_ws, size_t ws_size,
                              hipStream_t stream)
{
    const float* x_src  = (const float*)d_in[0];
    const float* x_dst  = (const float*)d_in[1];
    const int*   eidx   = (const int*)  d_in[2];   // [2,E]: src row then dst row
    const float* ew     = (const float*)d_in[3];
    const float* W_nei  = (const float*)d_in[4];
    const float* W_self = (const float*)d_in[5];
    const float* b_self = (const float*)d_in[6];
    float* out = (float*)d_out;

    const int* src = eidx;
    const int* dst = eidx + NE;

    // workspace layout (16B aligned)
    char* ws = (char*)d_ws;
    size_t off = 0;
    auto alloc = [&](size_t bytes) { char* p = ws + off; off += (bytes + 15) & ~(size_t)15; return p; };
    unsigned short* h = (unsigned short*)alloc((size_t)NN * FD * sizeof(unsigned short)); // 12.8 MB
    int*  gcursor  = (int*) alloc((size_t)NBP * sizeof(int));
    int*  rowstart = (int*) alloc((size_t)NN * sizeof(int));
    int*  rowend   = (int*) alloc((size_t)NN * sizeof(int));
    int2* sp       = (int2*)alloc((size_t)NBP * CAP * sizeof(int2));  // 16 MB
    int2* sp2      = (int2*)alloc((size_t)NBP * CAP * sizeof(int2));  // 16 MB
    const size_t need_main = off;
    const size_t need_h    = (size_t)NN * FD * sizeof(unsigned short);

    if (ws_size >= need_main) {
        hipMemsetAsync(gcursor, 0, (size_t)NBP * sizeof(int), stream);
        lin_both<<<LIN_GRID, 256, 0, stream>>>(x_src, x_dst, W_nei, W_self,
                                               b_self, h, out);
        kplace<<<NCH, 1024, 0, stream>>>(src, dst, ew, gcursor, sp);
        ksub  <<<NBK, 256, 0, stream>>>(sp, gcursor, sp2, rowstart, rowend);
        gather_rows<<<(NN * 64 + 255) / 256, 256, 0, stream>>>(h, rowstart,
                                                               rowend, sp2, out);
    } else if (ws_size >= need_h) {
        lin_both<<<LIN_GRID, 256, 0, stream>>>(x_src, x_dst, W_nei, W_self,
                                               b_self, h, out);
        scatter_edges<<<2048, 256, 0, stream>>>(h, eidx, ew, out);
    }
}

// Round 4
// 172.104 us; speedup vs baseline: 1.1796x; 1.0833x over previous
//
#include <hip/hip_runtime.h>

#define NN 100000   // N_SRC == N_DST
#define FD 64       // IN_SRC == IN_DST == OUT
#define NE 1250000  // E

#define RPB 128                         // dst rows per bucket
#define NBK ((NN + RPB - 1) / RPB)      // 782 buckets
#define NBP 1024                        // padded bucket count (pow2 >= NBK)
#define CAP 2048                        // fixed window per bucket (E[cnt]=1600, sd~40)
#define CH  8192                        // edges per partition block (8-edge=64B avg segments)
#define NCH ((NE + CH - 1) / CH)        // 153 partition blocks
#define NTILE (NN / 16)                 // 6250 MFMA tiles per matrix

#define TPW 2                           // tiles per wave in lin_both
#define NWM (NTILE / TPW)               // 3125 waves per matrix
#define LIN_GRID ((2 * NWM + 3) / 4)    // 1563 blocks (4 waves/block)

typedef __attribute__((ext_vector_type(8))) short bf16x8;
typedef __attribute__((ext_vector_type(4))) float f32x4;

__device__ __forceinline__ short cvt_bf16(float f) {   // RNE
    unsigned u = __float_as_uint(f);
    return (short)((u + 0x7FFFu + ((u >> 16) & 1u)) >> 16);
}
__device__ __forceinline__ float bf2f(unsigned short u) {
    return __uint_as_float(((unsigned)u) << 16);
}

// ---------- fused linears: 2 tiles/wave, W-in-reg, swapped-operand MFMA ----------
// Swapped mfma(wf, a): D[c][i] with col(lane&15)=i (x row), row(quad*4+r)=c-within-block.
// Each lane's acc[ct] = channels {ct*16+quad*4+r} of row (row0+m) -> contiguous
// float4/ushort4 stores. All 8 x-loads issued upfront; W converted once per wave.
// Block 0 also zeroes gcursor (completes before kplace by stream order).
__global__ __launch_bounds__(256) void lin_both(
    const float* __restrict__ x_src, const float* __restrict__ x_dst,
    const float* __restrict__ W_nei, const float* __restrict__ W_self,
    const float* __restrict__ b_self, unsigned short* __restrict__ hbuf,
    float* __restrict__ out, int* __restrict__ gcur)
{
    if (gcur && blockIdx.x == 0) {
        #pragma unroll
        for (int i = 0; i < NBP / 256; i++) gcur[threadIdx.x + i * 256] = 0;
    }
    const int lane = threadIdx.x & 63;
    const int m    = lane & 15;
    const int quad = lane >> 4;
    const int gw   = blockIdx.x * 4 + (threadIdx.x >> 6);
    if (gw >= 2 * NWM) return;
    const bool self = gw >= NWM;
    const int  wm   = self ? gw - NWM : gw;
    const float* __restrict__ x = self ? x_dst : x_src;
    const float* __restrict__ W = self ? W_self : W_nei;

    // all x loads for both tiles upfront: 8 independent float4 loads in flight
    const float* xb = x + (size_t)(wm * (TPW * 16) + m) * FD;
    float4 xv[TPW][4];
    #pragma unroll
    for (int t = 0; t < TPW; t++) {
        const float* xr = xb + (size_t)t * 16 * FD;
        xv[t][0] = *(const float4*)(xr + quad * 8);
        xv[t][1] = *(const float4*)(xr + quad * 8 + 4);
        xv[t][2] = *(const float4*)(xr + 32 + quad * 8);
        xv[t][3] = *(const float4*)(xr + 32 + quad * 8 + 4);
    }

    // W frags (A-operand of the swapped mfma): wf[kc][ct] = W[ct*16+m][kc*32+quad*8 ..+7]
    bf16x8 wf[2][4];
    #pragma unroll
    for (int kc = 0; kc < 2; kc++) {
        #pragma unroll
        for (int ct = 0; ct < 4; ct++) {
            const float4 w0 = *(const float4*)(W + (ct * 16 + m) * FD + kc * 32 + quad * 8);
            const float4 w1 = *(const float4*)(W + (ct * 16 + m) * FD + kc * 32 + quad * 8 + 4);
            bf16x8 f;
            f[0]=cvt_bf16(w0.x); f[1]=cvt_bf16(w0.y); f[2]=cvt_bf16(w0.z); f[3]=cvt_bf16(w0.w);
            f[4]=cvt_bf16(w1.x); f[5]=cvt_bf16(w1.y); f[6]=cvt_bf16(w1.z); f[7]=cvt_bf16(w1.w);
            wf[kc][ct] = f;
        }
    }

    float4 bv[4];
    if (self) {
        #pragma unroll
        for (int ct = 0; ct < 4; ct++)
            bv[ct] = *(const float4*)(b_self + ct * 16 + quad * 4);
    }

    #pragma unroll
    for (int t = 0; t < TPW; t++) {
        bf16x8 a0, a1;
        a0[0]=cvt_bf16(xv[t][0].x); a0[1]=cvt_bf16(xv[t][0].y);
        a0[2]=cvt_bf16(xv[t][0].z); a0[3]=cvt_bf16(xv[t][0].w);
        a0[4]=cvt_bf16(xv[t][1].x); a0[5]=cvt_bf16(xv[t][1].y);
        a0[6]=cvt_bf16(xv[t][1].z); a0[7]=cvt_bf16(xv[t][1].w);
        a1[0]=cvt_bf16(xv[t][2].x); a1[1]=cvt_bf16(xv[t][2].y);
        a1[2]=cvt_bf16(xv[t][2].z); a1[3]=cvt_bf16(xv[t][2].w);
        a1[4]=cvt_bf16(xv[t][3].x); a1[5]=cvt_bf16(xv[t][3].y);
        a1[6]=cvt_bf16(xv[t][3].z); a1[7]=cvt_bf16(xv[t][3].w);

        f32x4 acc[4];
        #pragma unroll
        for (int ct = 0; ct < 4; ct++) {
            f32x4 z = (f32x4){0.f, 0.f, 0.f, 0.f};
            z = __builtin_amdgcn_mfma_f32_16x16x32_bf16(wf[0][ct], a0, z, 0, 0, 0);
            z = __builtin_amdgcn_mfma_f32_16x16x32_bf16(wf[1][ct], a1, z, 0, 0, 0);
            acc[ct] = z;
        }

        const size_t rowbase = (size_t)(wm * (TPW * 16) + t * 16 + m) * FD;
        if (!self) {
            #pragma unroll
            for (int ct = 0; ct < 4; ct++) {
                ushort4 sv;
                sv.x = (unsigned short)cvt_bf16(acc[ct][0]);
                sv.y = (unsigned short)cvt_bf16(acc[ct][1]);
                sv.z = (unsigned short)cvt_bf16(acc[ct][2]);
                sv.w = (unsigned short)cvt_bf16(acc[ct][3]);
                *(ushort4*)(hbuf + rowbase + ct * 16 + quad * 4) = sv;
            }
        } else {
            #pragma unroll
            for (int ct = 0; ct < 4; ct++) {
                float4 v;
                v.x = acc[ct][0] + bv[ct].x;
                v.y = acc[ct][1] + bv[ct].y;
                v.z = acc[ct][2] + bv[ct].z;
                v.w = acc[ct][3] + bv[ct].w;
                *(float4*)(out + rowbase + ct * 16 + quad * 4) = v;
            }
        }
    }
}

// ---------- partition edges into fixed-capacity bucket windows ----------
// 1024 threads (16 waves/block, 2 blocks/CU), 8 edges/thread preloaded for ILP.
__global__ __launch_bounds__(1024) void kplace(
    const int* __restrict__ src, const int* __restrict__ dst,
    const float* __restrict__ ew, int* __restrict__ gcursor,
    int2* __restrict__ sp)
{
    __shared__ int cnt[NBP];
    const int t = threadIdx.x;            // 0..1023
    if (t < NBP) cnt[t] = 0;
    __syncthreads();
    const int e0 = blockIdx.x * CH;

    // pass 1: preload 8 dst values (coalesced, independent), then count
    int d[8];
    #pragma unroll
    for (int k = 0; k < 8; k++) {
        const int e = e0 + t + k * 1024;
        d[k] = (e < NE) ? dst[e] : -1;
    }
    #pragma unroll
    for (int k = 0; k < 8; k++)
        if (d[k] >= 0) atomicAdd(&cnt[d[k] >> 7], 1);
    __syncthreads();

    // reserve dense segments in this bucket's fixed window
    if (t < NBP) {
        const int c = cnt[t];
        cnt[t] = c ? (t * CAP + atomicAdd(&gcursor[t], c)) : 0;
    }
    __syncthreads();

    // pass 2: preload src/ew, then emit (8 stores in flight per thread)
    int s[8]; float w[8];
    #pragma unroll
    for (int k = 0; k < 8; k++) {
        const int e = e0 + t + k * 1024;
        if (e < NE) { s[k] = src[e]; w[k] = ew[e]; }
    }
    #pragma unroll
    for (int k = 0; k < 8; k++) {
        if (d[k] >= 0) {
            const int p = atomicAdd(&cnt[d[k] >> 7], 1);
            sp[p] = make_int2(s[k] | ((d[k] & (RPB - 1)) << 17),
                              __float_as_int(w[k]));
        }
    }
}

// ---------- fused counting-sort + gather: one block per bucket ----------
// Phase 1 (ksub-in-LDS): register-stage the bucket's sp window, histogram into
// hist[128], wave-0 scan, scatter into LDS ebuf (no sp2/rowstart globals).
// Phase 2 (gather v3 scheme): wave wv handles rows wv+8i; quad q takes edge
// k+4j+q via broadcast ds_read_b64; 16 lanes load the full 128B h-row as uint2.
// Per-row round-up reads past n hit either the NEXT row's edges (valid, finite,
// w=0) or the zeroed tail pad ebuf[cnt..cnt+15] (srow=0 -> finite h row 0, w=0).
// NOTE: w=0 masking only works if the gathered data is FINITE — uninitialized
// LDS decoding to bf16 NaN gives fmaf(NaN,0,acc)=NaN (the Round-3 bug).
__global__ __launch_bounds__(512) void sort_gather(
    const int2* __restrict__ sp, const int* __restrict__ gcursor,
    const unsigned short* __restrict__ h, float* __restrict__ out)
{
    __shared__ int2 ebuf[CAP + 16];
    __shared__ int hist[RPB];
    __shared__ int rs[RPB];
    __shared__ int cur[RPB];
    const int t = threadIdx.x;            // 0..511
    const int b = blockIdx.x;
    const int cnt = gcursor[b];
    const int s0 = b * CAP;

    if (t < RPB) hist[t] = 0;

    // register-stage this bucket's window (coalesced, 4 edges/thread)
    int2 ev[4]; int er[4];
    #pragma unroll
    for (int k = 0; k < 4; k++) {
        const int j = t + k * 512;
        if (j < cnt) { ev[k] = sp[s0 + j]; er[k] = ev[k].x >> 17; }
        else er[k] = -1;
    }
    __syncthreads();
    #pragma unroll
    for (int k = 0; k < 4; k++)
        if (er[k] >= 0) atomicAdd(&hist[er[k]], 1);
    __syncthreads();
    if (t < 64) {                         // wave 0 scans 2 bins per lane
        const int v0 = hist[2*t], v1 = hist[2*t + 1];
        const int s = v0 + v1;
        int inc = s;
        #pragma unroll
        for (int off = 1; off < 64; off <<= 1) {
            int u = __shfl_up(inc, off, 64);
            if (t >= off) inc += u;
        }
        const int ex = inc - s;
        rs[2*t]      = ex;       cur[2*t]     = ex;
        rs[2*t + 1]  = ex + v0;  cur[2*t + 1] = ex + v0;
    }
    __syncthreads();
    #pragma unroll
    for (int k = 0; k < 4; k++) {
        if (er[k] >= 0) {
            const int p = atomicAdd(&cur[er[k]], 1);
            ebuf[p] = ev[k];
        }
    }
    if (t < 16) ebuf[cnt + t] = make_int2(0, 0);  // zero the read-over tail pad
    __syncthreads();

    // phase 2: gather
    const int wv   = t >> 6;              // wave 0..7
    const int lane = t & 63;
    const int q    = lane >> 4;
    const int tc   = lane & 15;
    const unsigned tb = (unsigned)tc << 3;
    const int row0 = b * RPB;

    for (int i = 0; i < 16; i++) {
        const int r   = wv + i * 8;       // monotone in i per wave
        const int row = row0 + r;
        if (row >= NN) break;
        const int rsr = rs[r];
        const int n   = hist[r];
        float a0 = 0.f, a1 = 0.f, a2 = 0.f, a3 = 0.f;
        for (int k = 0; k < n; k += 16) {
            int2 ed[4];
            #pragma unroll
            for (int j = 0; j < 4; j++)
                ed[j] = ebuf[rsr + k + j * 4 + q];   // broadcast within quad
            uint2 dv[4]; float wv4[4];
            #pragma unroll
            for (int j = 0; j < 4; j++) {
                const unsigned off = (((unsigned)(ed[j].x & 0x1FFFF)) << 7) | tb;
                dv[j] = *(const uint2*)((const char*)h + off);
                wv4[j] = (k + j * 4 + q < n) ? __int_as_float(ed[j].y) : 0.f;
            }
            #pragma unroll
            for (int j = 0; j < 4; j++) {
                const float w = wv4[j];
                a0 = fmaf(__uint_as_float(dv[j].x << 16),         w, a0);
                a1 = fmaf(__uint_as_float(dv[j].x & 0xFFFF0000u), w, a1);
                a2 = fmaf(__uint_as_float(dv[j].y << 16),         w, a2);
                a3 = fmaf(__uint_as_float(dv[j].y & 0xFFFF0000u), w, a3);
            }
        }
        // cross-quad reduction
        a0 += __shfl_xor(a0, 16, 64); a1 += __shfl_xor(a1, 16, 64);
        a2 += __shfl_xor(a2, 16, 64); a3 += __shfl_xor(a3, 16, 64);
        a0 += __shfl_xor(a0, 32, 64); a1 += __shfl_xor(a1, 32, 64);
        a2 += __shfl_xor(a2, 32, 64); a3 += __shfl_xor(a3, 32, 64);
        if (q == 0) {                     // coalesced 256B float4 RMW
            float4* p = (float4*)(out + (size_t)row * FD + (tc << 2));
            float4 v = *p;
            v.x += a0; v.y += a1; v.z += a2; v.w += a3;
            *p = v;
        }
    }
}

// ---------- fallback (small ws): linears + atomic scatter ----------
__global__ __launch_bounds__(256) void scatter_edges(
    const unsigned short* __restrict__ h, const int* __restrict__ eidx,
    const float* __restrict__ ew, float* __restrict__ out)
{
    const int lane  = threadIdx.x & 63;
    const int gwave = (int)((blockIdx.x * blockDim.x + threadIdx.x) >> 6);
    const int nwave = (int)((gridDim.x * blockDim.x) >> 6);
    const int* __restrict__ src = eidx;
    const int* __restrict__ dst = eidx + NE;
    for (int e = gwave; e < NE; e += nwave) {
        const float v = bf2f(h[(size_t)src[e] * FD + lane]) * ew[e];
        atomicAdd(out + (size_t)dst[e] * FD + lane, v);
    }
}

extern "C" void kernel_launch(void* const* d_in, const int* in_sizes, int n_in,
                              void* d_out, int out_size, void* d_ws, size_t ws_size,
                              hipStream_t stream)
{
    const float* x_src  = (const float*)d_in[0];
    const float* x_dst  = (const float*)d_in[1];
    const int*   eidx   = (const int*)  d_in[2];   // [2,E]: src row then dst row
    const float* ew     = (const float*)d_in[3];
    const float* W_nei  = (const float*)d_in[4];
    const float* W_self = (const float*)d_in[5];
    const float* b_self = (const float*)d_in[6];
    float* out = (float*)d_out;

    const int* src = eidx;
    const int* dst = eidx + NE;

    // workspace layout (16B aligned); h MUST stay at ws base (pad-read bound)
    char* ws = (char*)d_ws;
    size_t off = 0;
    auto alloc = [&](size_t bytes) { char* p = ws + off; off += (bytes + 15) & ~(size_t)15; return p; };
    unsigned short* h = (unsigned short*)alloc((size_t)NN * FD * sizeof(unsigned short)); // 12.8 MB
    int*  gcursor  = (int*) alloc((size_t)NBP * sizeof(int));
    int2* sp       = (int2*)alloc((size_t)NBP * CAP * sizeof(int2));  // 16 MB
    const size_t need_main = off;
    const size_t need_h    = (size_t)NN * FD * sizeof(unsigned short);

    if (ws_size >= need_main) {
        lin_both<<<LIN_GRID, 256, 0, stream>>>(x_src, x_dst, W_nei, W_self,
                                               b_self, h, out, gcursor);
        kplace<<<NCH, 1024, 0, stream>>>(src, dst, ew, gcursor, sp);
        sort_gather<<<NBK, 512, 0, stream>>>(sp, gcursor, h, out);
    } else if (ws_size >= need_h) {
        lin_both<<<LIN_GRID, 256, 0, stream>>>(x_src, x_dst, W_nei, W_self,
                                               b_self, h, out, nullptr);
        scatter_edges<<<2048, 256, 0, stream>>>(h, eidx, ew, out);
    }
}